// Round 6
// baseline (718.086 us; speedup 1.0000x reference)
//
#include <hip/hip_runtime.h>
#include <hip/hip_bf16.h>

// ---------------------------------------------------------------------------
// HRAInjectedLinear: out = x @ (W * prod_i (I - 2 u_i u_i^T))^T
//   prep:  d_ij = hu_i . hu_j -> inv_i = rsqrt(d_ii), G_ij = d_ij inv_i inv_j
//   wuwn:  per W-row: y = (W row . u_j), recurrence v, Wn = bf16(row - 2 v u^T)
//          (single W sweep; W row held in registers)
//   cast_x: Xb = bf16(x)
//   gemm256: out = Xb @ Wn^T — 256x256 tile, 8 waves, 2-barrier counted-vmcnt
//          schedule, 32x32x16 MFMA, 16B-row-stride LDS layout (conflict-free,
//          no XOR), XCD swizzle, setprio.
// r5 post-mortem: [ks][row][32B] layout gave 2.5e7 bank conflicts on the
// 32x32 read pattern (32B-of-64B strided). New layout [ksec][row][16B]:
// fragment reads are contiguous 512B per half-wave = linear = conflict-free.
// ---------------------------------------------------------------------------

#define D_IN   4096
#define D_OUT  4096
#define R_HH   8
#define M_ROWS 8192   // B*S = 4*2048

typedef short bf16x8  __attribute__((ext_vector_type(8)));
typedef float f32x4   __attribute__((ext_vector_type(4)));
typedef float f32x16  __attribute__((ext_vector_type(16)));

__device__ inline unsigned short f2bf(float f) {
    unsigned int x = __float_as_uint(f);
    unsigned int lsb = (x >> 16) & 1u;
    x += 0x7fffu + lsb;                 // round-to-nearest-even
    return (unsigned short)(x >> 16);
}

__device__ inline void async16(const unsigned short* g, char* l) {
    __builtin_amdgcn_global_load_lds(
        (const __attribute__((address_space(1))) void*)g,
        (__attribute__((address_space(3))) void*)l,
        16, 0, 0);
}

// --- kernel 1: prep — raw Gram dots of hra_u columns -> G (normalized) + inv
__global__ __launch_bounds__(1024) void prep(const float* __restrict__ hu,
                                             float* __restrict__ G,
                                             float* __restrict__ inv8) {
    float d[36];
    #pragma unroll
    for (int p = 0; p < 36; p++) d[p] = 0.f;
    for (int r = threadIdx.x; r < D_IN; r += 1024) {
        const float4* h4 = (const float4*)&hu[r * R_HH];
        float4 a = h4[0], b = h4[1];
        float h[8] = {a.x, a.y, a.z, a.w, b.x, b.y, b.z, b.w};
        int p = 0;
        #pragma unroll
        for (int i = 0; i < 8; i++)
            #pragma unroll
            for (int j = i; j < 8; j++)
                d[p++] += h[i] * h[j];
    }
    #pragma unroll
    for (int p = 0; p < 36; p++)
        #pragma unroll
        for (int off = 32; off > 0; off >>= 1)
            d[p] += __shfl_down(d[p], off, 64);
    __shared__ float red[16 * 36];
    const int wave = threadIdx.x >> 6, lane = threadIdx.x & 63;
    if (lane == 0)
        #pragma unroll
        for (int p = 0; p < 36; p++) red[wave * 36 + p] = d[p];
    __syncthreads();
    __shared__ float dd[36];
    if (threadIdx.x < 36) {
        float s = 0.f;
        #pragma unroll
        for (int w = 0; w < 16; w++) s += red[w * 36 + threadIdx.x];
        dd[threadIdx.x] = s;
    }
    __syncthreads();
    auto idx = [](int a, int b) { return a * 8 + b - (a * (a + 1)) / 2; };
    if (threadIdx.x < 64) {
        const int i = threadIdx.x >> 3, j = threadIdx.x & 7;
        const int a = i < j ? i : j, b = i < j ? j : i;
        const float gi = rsqrtf(dd[idx(i, i)]);
        const float gj = rsqrtf(dd[idx(j, j)]);
        G[threadIdx.x] = dd[idx(a, b)] * gi * gj;
        if (j == 0) inv8[i] = gi;
    }
}

// --- kernel 2: wuwn — fused Y = W U, recurrence, Wn = bf16(W - 2 V U^T) ----
// One block per W row; the row is held in registers across all three steps,
// so W is swept from HBM exactly once.
__global__ __launch_bounds__(256) void wuwn(
    const float* __restrict__ W, const float* __restrict__ hu,
    const float* __restrict__ inv8, const float* __restrict__ G,
    unsigned short* __restrict__ Wn) {
    const int o = blockIdx.x;
    const int t = threadIdx.x;
    __shared__ float gs[64];
    __shared__ float is[8];
    if (t < 64) gs[t] = G[t];
    if (t >= 64 && t < 72) is[t - 64] = inv8[t - 64];

    // dot phase: thread t covers float4 chunks {t, t+256, t+512, t+768}
    const float4* wrow4 = (const float4*)(W + (size_t)o * D_IN);
    float4 wreg[4];
    float acc[8] = {0,0,0,0,0,0,0,0};
    #pragma unroll
    for (int c = 0; c < 4; c++) {
        const int k4 = t + c * 256;
        wreg[c] = wrow4[k4];
        float wa[4] = {wreg[c].x, wreg[c].y, wreg[c].z, wreg[c].w};
        #pragma unroll
        for (int e = 0; e < 4; e++) {
            const int k = k4 * 4 + e;
            const float4* u4 = (const float4*)&hu[k * R_HH];
            float4 ua = u4[0], ub = u4[1];
            acc[0] += wa[e]*ua.x; acc[1] += wa[e]*ua.y;
            acc[2] += wa[e]*ua.z; acc[3] += wa[e]*ua.w;
            acc[4] += wa[e]*ub.x; acc[5] += wa[e]*ub.y;
            acc[6] += wa[e]*ub.z; acc[7] += wa[e]*ub.w;
        }
    }
    __shared__ float red[8 * 256];
    #pragma unroll
    for (int j = 0; j < 8; j++) red[j * 256 + t] = acc[j];
    __syncthreads();
    for (int off = 128; off > 0; off >>= 1) {
        if (t < off)
            #pragma unroll
            for (int j = 0; j < 8; j++)
                red[j * 256 + t] += red[j * 256 + t + off];
        __syncthreads();
    }
    // all threads: y (scaled), recurrence, v-scale  (redundant, ~100 FLOP)
    float v[8];
    #pragma unroll
    for (int i = 0; i < 8; i++) {
        float ti = red[i * 256] * is[i];
        #pragma unroll
        for (int j = 0; j < 8; j++)
            if (j < i) ti -= 2.0f * gs[j * 8 + i] * v[j];
        v[i] = ti;
    }
    #pragma unroll
    for (int i = 0; i < 8; i++) v[i] *= is[i];

    // update phase: reuse wreg, re-read hu (L1/L2-hot)
    ushort4* wnrow = (ushort4*)(Wn + (size_t)o * D_IN);
    #pragma unroll
    for (int c = 0; c < 4; c++) {
        const int k4 = t + c * 256;
        float wa[4] = {wreg[c].x, wreg[c].y, wreg[c].z, wreg[c].w};
        float out[4];
        #pragma unroll
        for (int e = 0; e < 4; e++) {
            const int k = k4 * 4 + e;
            const float4* u4 = (const float4*)&hu[k * R_HH];
            float4 ua = u4[0], ub = u4[1];
            float corr = v[0]*ua.x + v[1]*ua.y + v[2]*ua.z + v[3]*ua.w
                       + v[4]*ub.x + v[5]*ub.y + v[6]*ub.z + v[7]*ub.w;
            out[e] = wa[e] - 2.0f * corr;
        }
        ushort4 r;
        r.x = f2bf(out[0]); r.y = f2bf(out[1]); r.z = f2bf(out[2]); r.w = f2bf(out[3]);
        wnrow[k4] = r;
    }
}

// --- kernel 3: Xb = bf16(x), grid-stride ------------------------------------
__global__ void cast_x(const float4* __restrict__ x, ushort4* __restrict__ xb, int n4) {
    for (int g = blockIdx.x * 256 + threadIdx.x; g < n4; g += gridDim.x * 256) {
        float4 f = x[g];
        ushort4 r;
        r.x = f2bf(f.x); r.y = f2bf(f.y); r.z = f2bf(f.z); r.w = f2bf(f.w);
        xb[g] = r;
    }
}

// --- kernel 4: C = A B^T, 256x256 tile, 8 waves, 2-barrier counted-vmcnt ---
//
// LDS (dynamic, 128 KiB), 16B-row-stride layout, NO swizzle:
//   A: [buf][ksec 0..7][row 0..255][16B]   bytes [buf*32768, +32768)
//   B: same at +65536
//   ksec = global k-byte/16 within the K-tile (K-tile = 64 elem = 128B/row).
//
// Staging (global_load_lds, linear dest): statement p in 0..3 writes LDS
//   bytes p*8192 + tid*16 = ksec*4096 + row*16 with ksec=2p+(tid>>8),
//   row=tid&255; per-lane global source = (row)*K + kt*64 + p*16e + (tid>>8)*8e.
// Fragment read (32x32x16, step s=0..3): ksec = 2s+(lane>>5),
//   addr = buf + s*8192 + (lane>>5)*4096 + (frag*32 + base + (lane&31))*16
//   -> lower/upper 32 lanes each read a CONTIGUOUS 512B block = conflict-free.
//
// Schedule per K-tile kt (buf bb = kt&1) — 2 barriers, split by A-rows
// (ALL B reads in region 1 -> bb.B restage after mid-barrier is legal):
//   region 1: ds a(i=0,1)x4s (8) + b(all)x4s (8); stageA(kt+1,0);
//     8 MFMA (i01,s01); stageA(kt+1,1); 8 MFMA (i01,s23); mid-barrier
//   region 2: ds a(i=2,3)x4s (8); stageB(kt+2,0); 8 MFMA (i23,s01);
//     stageB(kt+2,1); 8 MFMA (i23,s23); vmcnt(4) [keeps B(kt+2) 4 loads in
//     flight; vmcnt(0) last 2 tiles]; boundary barrier.
// ---------------------------------------------------------------------------
__global__ __launch_bounds__(512, 2) void gemm256(
    const unsigned short* __restrict__ A,   // [M][K] bf16 bits
    const unsigned short* __restrict__ B,   // [N][K] bf16 bits
    float* __restrict__ C) {                // [M][N]
    constexpr int K  = D_IN;
    constexpr int NN = D_OUT;
    constexpr int NT = K / 64;              // 64 K-tiles

    extern __shared__ __align__(16) char lds[];

    const int tid  = threadIdx.x;
    const int lane = tid & 63;
    const int wave = tid >> 6;

    // bijective XCD swizzle (512 blocks, 512 % 8 == 0); tm-major chunks
    const int bid = blockIdx.x;
    const int cpx = gridDim.x >> 3;
    const int swz = (bid & 7) * cpx + (bid >> 3);
    const int TN  = NN / 256;               // 16
    const int tm  = swz / TN, tn = swz - tm * TN;

    const size_t rA0 = (size_t)tm * 256;
    const size_t rB0 = (size_t)tn * 256;

    const int wr = (wave >> 2) * 128;       // 2 waves in M
    const int wc = (wave & 3) * 64;         // 4 waves in N

    // staging: statement p covers ksec {2p, 2p+1}; thread -> (row, hi)
    const int sRow2 = tid & 255;            // 0..255
    const int sHi   = tid >> 8;             // 0/1 -> +8 elements
    const unsigned short* gA2 = A + (rA0 + sRow2) * (size_t)K + sHi * 8;
    const unsigned short* gB2 = B + (rB0 + sRow2) * (size_t)K + sHi * 8;

    auto stageA = [&](int kt, int h) {      // h: k-half (statements p=2h,2h+1)
        const unsigned short* g = gA2 + kt * 64 + h * 32;
        char* l = lds + (kt & 1) * 32768 + h * 16384 + tid * 16;
        async16(g, l);                      // p = 2h
        async16(g + 16, l + 8192);          // p = 2h+1
    };
    auto stageB = [&](int kt, int h) {
        const unsigned short* g = gB2 + kt * 64 + h * 32;
        char* l = lds + 65536 + (kt & 1) * 32768 + h * 16384 + tid * 16;
        async16(g, l);
        async16(g + 16, l + 8192);
    };

    // reader constants (32x32x16 fragments; contiguous 512B per half-wave)
    const int kAoff = (lane >> 5) * 4096 + (wr + (lane & 31)) * 16;
    const int kBoff = 65536 + (lane >> 5) * 4096 + (wc + (lane & 31)) * 16;

    auto LDA = [&](int bb, int i, int s) -> bf16x8 {
        return *(const bf16x8*)(lds + bb * 32768 + s * 8192 + i * 512 + kAoff);
    };
    auto LDB = [&](int bb, int j, int s) -> bf16x8 {
        return *(const bf16x8*)(lds + bb * 32768 + s * 8192 + j * 512 + kBoff);
    };

    f32x16 acc[4][2];
    #pragma unroll
    for (int i = 0; i < 4; i++)
        #pragma unroll
        for (int j = 0; j < 2; j++)
            acc[i][j] = (f32x16){0.f,0.f,0.f,0.f,0.f,0.f,0.f,0.f,
                                 0.f,0.f,0.f,0.f,0.f,0.f,0.f,0.f};

    // ---- prologue: tile0 fully + tile1 B halves; keep 4 loads in flight ---
    stageA(0, 0); stageA(0, 1); stageB(0, 0); stageB(0, 1);
    stageB(1, 0); stageB(1, 1);
    asm volatile("s_waitcnt vmcnt(4)" ::: "memory");   // tile 0 landed
    __builtin_amdgcn_s_barrier();

    #pragma unroll 2
    for (int kt = 0; kt < NT; ++kt) {
        const int bb = kt & 1;

        bf16x8 a[2][4], b[2][4];
        // ---- region 1: reads a(i=0,1) + ALL b; A-stages; 16 MFMA (i=0,1) --
        #pragma unroll
        for (int i = 0; i < 2; i++)
            #pragma unroll
            for (int s = 0; s < 4; s++) a[i][s] = LDA(bb, i, s);
        #pragma unroll
        for (int j = 0; j < 2; j++)
            #pragma unroll
            for (int s = 0; s < 4; s++) b[j][s] = LDB(bb, j, s);
        if (kt + 1 < NT) stageA(kt + 1, 0);
        __builtin_amdgcn_s_setprio(1);
        #pragma unroll
        for (int s = 0; s < 2; s++)
            #pragma unroll
            for (int i = 0; i < 2; i++)
                #pragma unroll
                for (int j = 0; j < 2; j++)
                    acc[i][j] = __builtin_amdgcn_mfma_f32_32x32x16_bf16(a[i][s], b[j][s], acc[i][j], 0, 0, 0);
        __builtin_amdgcn_s_setprio(0);
        if (kt + 1 < NT) stageA(kt + 1, 1);
        __builtin_amdgcn_s_setprio(1);
        #pragma unroll
        for (int s = 2; s < 4; s++)
            #pragma unroll
            for (int i = 0; i < 2; i++)
                #pragma unroll
                for (int j = 0; j < 2; j++)
                    acc[i][j] = __builtin_amdgcn_mfma_f32_32x32x16_bf16(a[i][s], b[j][s], acc[i][j], 0, 0, 0);
        __builtin_amdgcn_s_setprio(0);

        // ---- mid barrier: all bb.B reads done -> release bb.B -------------
        asm volatile("" ::: "memory");
        __builtin_amdgcn_s_barrier();
        asm volatile("" ::: "memory");

        // ---- region 2: reads a(i=2,3); B-stages; 16 MFMA (i=2,3) ----------
        #pragma unroll
        for (int i = 0; i < 2; i++)
            #pragma unroll
            for (int s = 0; s < 4; s++) a[i][s] = LDA(bb, 2 + i, s);
        if (kt + 2 < NT) stageB(kt + 2, 0);
        __builtin_amdgcn_s_setprio(1);
        #pragma unroll
        for (int s = 0; s < 2; s++)
            #pragma unroll
            for (int i = 0; i < 2; i++)
                #pragma unroll
                for (int j = 0; j < 2; j++)
                    acc[2 + i][j] = __builtin_amdgcn_mfma_f32_32x32x16_bf16(a[i][s], b[j][s], acc[2 + i][j], 0, 0, 0);
        __builtin_amdgcn_s_setprio(0);
        if (kt + 2 < NT) stageB(kt + 2, 1);
        __builtin_amdgcn_s_setprio(1);
        #pragma unroll
        for (int s = 2; s < 4; s++)
            #pragma unroll
            for (int i = 0; i < 2; i++)
                #pragma unroll
                for (int j = 0; j < 2; j++)
                    acc[2 + i][j] = __builtin_amdgcn_mfma_f32_32x32x16_bf16(a[i][s], b[j][s], acc[2 + i][j], 0, 0, 0);
        __builtin_amdgcn_s_setprio(0);

        // ---- boundary: per-wave counted drain, then global release --------
        if (kt < NT - 2)
            asm volatile("s_waitcnt vmcnt(4)" ::: "memory");  // keep B(kt+2,*) in flight
        else
            asm volatile("s_waitcnt vmcnt(0)" ::: "memory");  // tail drain
        __builtin_amdgcn_s_barrier();
    }

    // epilogue: 32x32 C/D layout col=lane&31, row=(reg&3)+8*(reg>>2)+4*(lane>>5)
    const int ccol = lane & 31;
    const int rsub = 4 * (lane >> 5);
    #pragma unroll
    for (int i = 0; i < 4; i++) {
        #pragma unroll
        for (int j = 0; j < 2; j++) {
            size_t base = (rA0 + wr + i * 32 + rsub) * (size_t)NN
                        + (rB0 + wc + j * 32 + ccol);
            #pragma unroll
            for (int r = 0; r < 16; r++) {
                const int row = (r & 3) + 8 * (r >> 2);
                C[base + (size_t)row * NN] = acc[i][j][r];
            }
        }
    }
}

// ---------------------------------------------------------------------------
extern "C" void kernel_launch(void* const* d_in, const int* in_sizes, int n_in,
                              void* d_out, int out_size, void* d_ws, size_t ws_size,
                              hipStream_t stream) {
    const float* x      = (const float*)d_in[0];   // [4,2048,4096]
    const float* weight = (const float*)d_in[1];   // [4096,4096]
    const float* hra_u  = (const float*)d_in[2];   // [4096,8]
    float* out = (float*)d_out;                    // [4,2048,4096]

    // workspace layout (all 16B aligned)
    char* w = (char*)d_ws;
    unsigned short* Xb = (unsigned short*)w;                              // 64 MB
    unsigned short* Wn = (unsigned short*)(w + (size_t)64 * 1024 * 1024); // 32 MB
    float* G   = (float*)(w + (size_t)96 * 1024 * 1024);
    float* inv = G + 64;

    static int attr_done = 0;
    if (!attr_done) {
        hipFuncSetAttribute((const void*)gemm256,
                            hipFuncAttributeMaxDynamicSharedMemorySize, 131072);
        attr_done = 1;
    }

    prep<<<1, 1024, 0, stream>>>(hra_u, G, inv);
    wuwn<<<D_OUT, 256, 0, stream>>>(weight, hra_u, inv, G, Wn);

    const int n4 = M_ROWS * D_IN / 4;
    cast_x<<<4096, 256, 0, stream>>>((const float4*)x, (ushort4*)Xb, n4);

    gemm256<<<dim3((M_ROWS / 256) * (D_OUT / 256)), 512, 131072, stream>>>(Xb, Wn, out);
}